// Round 7
// baseline (280.483 us; speedup 1.0000x reference)
//
#include <hip/hip_runtime.h>
#include <hip/hip_bf16.h>
#include <math.h>

#define B_TOTAL 8192
#define NN      82
#define HH      10
#define OUTC    5
#define TSTEP   3
#define NB      2            // batches per block; cols = NB*96 = 192
#define THREADS 256
#define KP      96           // padded adjacency dim (3 x 32)
#define CP      204          // ACT row stride in floats (row span 192+12 = 204, exact)
#define ACT_FLOATS (32 * CP) // 6528 floats = 26,112 B
#define WS_F    6528         // wout(100)+bout(5) at float offset 6528
#define GS_F    6640         // gate A-frag tables: 3072 bf16 = 1536 floats (16B aligned)
#define SMEM_FLOATS 8176     // 32,704 B -> 5 blocks/CU (granule-rounded 32,768)
// ACT plane rows (row index == MFMA K index for the gate matvecs):
//   0..9  = a_in[h][col]      10..19 = a_out[h][col]
//   20..29 = fn[h][col]  (becomes rf[h][col] mid-step, then fn_new)
//   30 = ones (bias row)      31 = zeros (K-pad row)
// col = m*96 + node (pad cols 82..95 per batch stay zero / masked)

typedef __bf16 bf16x8 __attribute__((ext_vector_type(8)));
typedef float  f32x4  __attribute__((ext_vector_type(4)));

__device__ __forceinline__ int aidx(int r, int c) {
    // +4*(row&3) float swizzle spreads same-column cross-row reads over banks;
    // injective because |col+swz| < CP. 16B alignment preserved (4-float shifts).
    return r * CP + ((r & 3) << 2) + c;
}
__device__ __forceinline__ float sigmoid_(float x) {
    return 1.0f / (1.0f + __expf(-x));
}
__device__ __forceinline__ float tanh_(float x) {
    float e = __expf(2.0f * x);
    return 1.0f - 2.0f / (e + 1.0f);
}

// d_ws layout: EXACTLY the r0-r5 proven 73,728 B (adjP hi/lo only).
// r6 grew this to 79.9 KB and the overflow corrupted the adjacent x buffer
// (out_fn absmax 468 = bf16-garbage-as-float surviving the bounded GRU update).
__global__ void prep_adj_kernel(const float* __restrict__ in_adj,
                                const float* __restrict__ out_adj,
                                __hip_bfloat16* __restrict__ adjP) {
    int idx = blockIdx.x * blockDim.x + threadIdx.x;
    if (idx < 2 * KP * KP) {
        int a   = idx / (KP * KP);
        int rem = idx - a * (KP * KP);
        int i = rem / KP;
        int j = rem - i * KP;
        float v = 0.0f;
        if (i < NN && j < NN) v = (a == 0) ? in_adj[i * NN + j] : out_adj[i * NN + j];
        __hip_bfloat16 hi = __float2bfloat16(v);
        __hip_bfloat16 lo = __float2bfloat16(v - __bfloat162float(hi));
        adjP[idx]               = hi;
        adjP[2 * KP * KP + idx] = lo;
    }
}

extern "C" __global__ __launch_bounds__(THREADS, 5)
void ggnn_kernel(const float* __restrict__ x,
                 const __hip_bfloat16* __restrict__ adjP,
                 const float* __restrict__ w3w, const float* __restrict__ b3w,
                 const float* __restrict__ w3u, const float* __restrict__ b3u,
                 const float* __restrict__ w4w, const float* __restrict__ b4w,
                 const float* __restrict__ w5w, const float* __restrict__ b5w,
                 const float* __restrict__ w5u, const float* __restrict__ b5u,
                 const float* __restrict__ wout, const float* __restrict__ bout,
                 float* __restrict__ out0, float* __restrict__ out_fn)
{
    __shared__ __align__(16) float smemF[SMEM_FLOATS];
    float* actF = smemF;
    float* wS   = smemF + WS_F;
    __hip_bfloat16* gS = reinterpret_cast<__hip_bfloat16*>(smemF + GS_F);

    const int t     = threadIdx.x;
    const int bbase = blockIdx.x * NB;
    const int lane  = t & 63;
    const int w     = t >> 6;            // wave 0..3
    const int lo16  = lane & 15;
    const int quad  = lane >> 4;

    // ---- per-wave adjacency combo mapping (3 combos per wave) ----
    int ntile_c[3], adj_c[3], Boff[3];
    #pragma unroll
    for (int c = 0; c < 3; ++c) {
        int co = w * 3 + c;
        int nt = co >> 1;
        int ad = co & 1;
        ntile_c[c] = nt;
        adj_c[c]   = ad;
        Boff[c] = ad * KP * KP + (nt * 16 + lo16) * KP + quad * 8;
    }
    // agg A-frag row: h = lo16; rows >= 10 clamp into ones(30)/zero(31) rows,
    // which feed only the discarded C rows 10..15.
    const int arow = 20 + ((lo16 < 12) ? lo16 : 11);

    // ---- init: zero plane, stage wout/bout, build gate A-frag tables in LDS ----
    for (int i = t; i < ACT_FLOATS; i += THREADS) actF[i] = 0.0f;
    if (t < 100) wS[t] = wout[t];
    if (t < OUTC) wS[100 + t] = bout[t];
    // gate tables: 3 gates x {hi,lo} x 16 rows x 32 kc. A[row=h][kc]:
    // kc<20 -> W.av ; 20..29 -> U.(fn|rf) ; 30 -> bias (x ones row) ; 31 -> 0
    for (int e2 = t; e2 < 3072; e2 += THREADS) {
        int g   = e2 / 1024;             // 0=z 1=r 2=h
        int rem = e2 - g * 1024;
        int hl  = rem >> 9;              // 0=hi 1=lo
        int e   = rem & 511;
        int row = e >> 5;
        int kc  = e & 31;
        const float* wW = (g == 0) ? w3w : (g == 1) ? w4w : w5w;
        const float* wU = (g == 2) ? w5u : w3u;   // r gate reuses w3u (reference bug)
        const float* bW = (g == 0) ? b3w : (g == 1) ? b4w : b5w;
        const float* bU = (g == 2) ? b5u : b3u;   // r bias: b4w + b3u (bug-faithful)
        float v = 0.0f;
        if (row < HH) {
            if (kc < 20)       v = wW[row * 20 + kc];
            else if (kc < 30)  v = wU[row * 10 + (kc - 20)];
            else if (kc == 30) v = bW[row] + bU[row];
        }
        __hip_bfloat16 hi = __float2bfloat16(v);
        __hip_bfloat16 lo = __float2bfloat16(v - __bfloat162float(hi));
        gS[(g * 2 + hl) * 512 + e] = hl ? lo : hi;
    }
    __syncthreads();                      // zero/gS done before scatter-fills
    if (t < 192) actF[aidx(30, t)] = 1.0f;
    for (int idx = t; idx < NB * NN * HH; idx += THREADS) {
        int b_l = idx / (NN * HH);
        int rem = idx - b_l * (NN * HH);
        int j   = rem / HH;
        int h   = rem - j * HH;
        actF[aidx(20 + h, b_l * 96 + j)] = x[(size_t)bbase * NN * HH + idx];
    }

    #pragma unroll 1
    for (int step = 0; step < TSTEP; ++step) {
        __syncthreads();   // [1] fn rows (and at step 0: init) visible to all waves

        // ======== AGGREGATION: av rows 0..19 <- fn rows 20..29 x adjP ========
        // A rows (20..31) disjoint from C rows (0..19): write-as-you-go.
        f32x4 acc[NB][3];
        #pragma unroll
        for (int m = 0; m < NB; ++m)
            #pragma unroll
            for (int c = 0; c < 3; ++c) acc[m][c] = (f32x4){0, 0, 0, 0};

        #pragma unroll 1
        for (int k = 0; k < 3; ++k) {
            #pragma unroll
            for (int m = 0; m < NB; ++m) {
                const float* ap = actF + aidx(arow, m * 96 + quad * 8 + k * 32);
                f32x4 a0 = *reinterpret_cast<const f32x4*>(ap);
                f32x4 a1 = *reinterpret_cast<const f32x4*>(ap + 4);
                bf16x8 ah, al;
                #pragma unroll
                for (int e = 0; e < 4; ++e) {
                    __bf16 h0 = (__bf16)a0[e];
                    __bf16 h1 = (__bf16)a1[e];
                    ah[e]     = h0;
                    ah[4 + e] = h1;
                    al[e]     = (__bf16)(a0[e] - (float)h0);
                    al[4 + e] = (__bf16)(a1[e] - (float)h1);
                }
                #pragma unroll
                for (int c = 0; c < 3; ++c) {
                    const __hip_bfloat16* bp = adjP + Boff[c] + k * 32;
                    bf16x8 bh = *reinterpret_cast<const bf16x8*>(bp);
                    bf16x8 bl = *reinterpret_cast<const bf16x8*>(bp + 2 * KP * KP);
                    acc[m][c] = __builtin_amdgcn_mfma_f32_16x16x32_bf16(ah, bh, acc[m][c], 0, 0, 0);
                    acc[m][c] = __builtin_amdgcn_mfma_f32_16x16x32_bf16(al, bh, acc[m][c], 0, 0, 0);
                    acc[m][c] = __builtin_amdgcn_mfma_f32_16x16x32_bf16(ah, bl, acc[m][c], 0, 0, 0);
                }
            }
        }
        // C-write: row = adj*10 + h (h = quad*4+r), col = m*96 + nt*16 + lo16
        #pragma unroll
        for (int m = 0; m < NB; ++m) {
            #pragma unroll
            for (int c = 0; c < 3; ++c) {
                int ccol  = m * 96 + ntile_c[c] * 16 + lo16;
                int rbase = adj_c[c] * 10;
                if (quad < 2) {
                    #pragma unroll
                    for (int r = 0; r < 4; ++r)
                        actF[aidx(rbase + quad * 4 + r, ccol)] = acc[m][c][r];
                } else if (quad == 2) {
                    actF[aidx(rbase + 8, ccol)] = acc[m][c][0];
                    actF[aidx(rbase + 9, ccol)] = acc[m][c][1];
                }
            }
        }

        __syncthreads();   // [2] av rows visible (cross-wave)

        // ======== GATES via MFMA: K-rows = [av(20); fn|rf(10); ones; zero] ====
        #pragma unroll 1
        for (int tt = 0; tt < 3; ++tt) {
            const int col  = 48 * w + 16 * tt + lo16;
            const int cmod = (col >= 96) ? (col - 96) : col;
            const bool colv = (cmod < NN);

            // --- B1 from ACT columns (fn variant), fp32 -> hi/lo bf16 ---
            bf16x8 bh, bl;
            #pragma unroll
            for (int jj = 0; jj < 8; ++jj) {
                float v = actF[aidx(quad * 8 + jj, col)];
                __bf16 h_ = (__bf16)v;
                bh[jj] = h_;
                bl[jj] = (__bf16)(v - (float)h_);
            }
            f32x4 az = {0, 0, 0, 0}, ar = {0, 0, 0, 0};
            {
                bf16x8 WH = *reinterpret_cast<const bf16x8*>(&gS[0 * 512 + lo16 * 32 + quad * 8]);
                bf16x8 WL = *reinterpret_cast<const bf16x8*>(&gS[1 * 512 + lo16 * 32 + quad * 8]);
                az = __builtin_amdgcn_mfma_f32_16x16x32_bf16(WH, bh, az, 0, 0, 0);
                az = __builtin_amdgcn_mfma_f32_16x16x32_bf16(WL, bh, az, 0, 0, 0);
                az = __builtin_amdgcn_mfma_f32_16x16x32_bf16(WH, bl, az, 0, 0, 0);
            }
            {
                bf16x8 WH = *reinterpret_cast<const bf16x8*>(&gS[2 * 512 + lo16 * 32 + quad * 8]);
                bf16x8 WL = *reinterpret_cast<const bf16x8*>(&gS[3 * 512 + lo16 * 32 + quad * 8]);
                ar = __builtin_amdgcn_mfma_f32_16x16x32_bf16(WH, bh, ar, 0, 0, 0);
                ar = __builtin_amdgcn_mfma_f32_16x16x32_bf16(WL, bh, ar, 0, 0, 0);
                ar = __builtin_amdgcn_mfma_f32_16x16x32_bf16(WH, bl, ar, 0, 0, 0);
            }
            // elementwise: sigmoid, rf = sig(r)*fn  (rf at pad cols = sig*0 = 0)
            float zs[4], fc[4];
            #pragma unroll
            for (int r = 0; r < 4; ++r) {
                int h = quad * 4 + r;
                if (h < HH) {
                    zs[r] = sigmoid_(az[r]);
                    fc[r] = actF[aidx(20 + h, col)];
                    actF[aidx(20 + h, col)] = sigmoid_(ar[r]) * fc[r];   // rf
                }
            }

            // rf producer lanes (quad 0..2) and consumer lanes (quad 2..3) DIFFER.
            // Per-lane the addresses are provably disjoint (20+4q+r = 8q+jj is
            // impossible for q<4), so the compiler may legally hoist the B2 reads
            // above the rf writes — the dependency is cross-lane only. A real
            // barrier is required. [r6 root cause #2]
            __syncthreads();

            // --- B2 rebuild: rows 20..29 now rf ---
            #pragma unroll
            for (int jj = 0; jj < 8; ++jj) {
                float v = actF[aidx(quad * 8 + jj, col)];
                __bf16 h_ = (__bf16)v;
                bh[jj] = h_;
                bl[jj] = (__bf16)(v - (float)h_);
            }
            f32x4 ah_ = {0, 0, 0, 0};
            {
                bf16x8 WH = *reinterpret_cast<const bf16x8*>(&gS[4 * 512 + lo16 * 32 + quad * 8]);
                bf16x8 WL = *reinterpret_cast<const bf16x8*>(&gS[5 * 512 + lo16 * 32 + quad * 8]);
                ah_ = __builtin_amdgcn_mfma_f32_16x16x32_bf16(WH, bh, ah_, 0, 0, 0);
                ah_ = __builtin_amdgcn_mfma_f32_16x16x32_bf16(WL, bh, ah_, 0, 0, 0);
                ah_ = __builtin_amdgcn_mfma_f32_16x16x32_bf16(WH, bl, ah_, 0, 0, 0);
            }
            // fn_new = fn + z*(tanh(h) - fn); masked to valid cols (pad stays 0)
            #pragma unroll
            for (int r = 0; r < 4; ++r) {
                int h = quad * 4 + r;
                if (h < HH && colv) {
                    float hv = tanh_(ah_[r]);
                    actF[aidx(20 + h, col)] = fc[r] + zs[r] * (hv - fc[r]);
                }
            }
            // fn_new/rf writes of tile tt never alias tile tt+1's reads
            // (col sets disjoint per wave) — next cross-wave publish is [1].
        }
    }

    __syncthreads();   // fn final visible for epilogue

    // ---- epilogue: out0 = tanh([fn, x] @ wout^T + bout), out_fn = fn ----
    if (t < NB * 96 && (t % 96) < NN) {
        int m = t / 96, node = t - m * 96;
        size_t row = (size_t)(bbase + m) * NN + node;
        float fnv[HH];
        #pragma unroll
        for (int h = 0; h < HH; ++h) fnv[h] = actF[aidx(20 + h, t)];
        const float* xr = x + row * HH;
        float xi[HH];
        #pragma unroll
        for (int p = 0; p < 5; ++p) {
            float2 v = reinterpret_cast<const float2*>(xr)[p];
            xi[2 * p] = v.x; xi[2 * p + 1] = v.y;
        }
        #pragma unroll
        for (int c = 0; c < OUTC; ++c) {
            float s = wS[100 + c];
            #pragma unroll
            for (int p = 0; p < HH; ++p)
                s += wS[c * 20 + p] * fnv[p] + wS[c * 20 + 10 + p] * xi[p];
            out0[row * OUTC + c] = tanh_(s);
        }
        #pragma unroll
        for (int p = 0; p < 5; ++p)
            reinterpret_cast<float2*>(out_fn + row * HH)[p] =
                make_float2(fnv[2 * p], fnv[2 * p + 1]);
    }
}

extern "C" void kernel_launch(void* const* d_in, const int* in_sizes, int n_in,
                              void* d_out, int out_size, void* d_ws, size_t ws_size,
                              hipStream_t stream) {
    const float* x       = (const float*)d_in[0];
    const float* in_adj  = (const float*)d_in[1];
    const float* out_adj = (const float*)d_in[2];
    const float* w3w = (const float*)d_in[3];
    const float* b3w = (const float*)d_in[4];
    const float* w3u = (const float*)d_in[5];
    const float* b3u = (const float*)d_in[6];
    const float* w4w = (const float*)d_in[7];
    const float* b4w = (const float*)d_in[8];
    const float* w5w = (const float*)d_in[9];
    const float* b5w = (const float*)d_in[10];
    const float* w5u = (const float*)d_in[11];
    const float* b5u = (const float*)d_in[12];
    const float* wout = (const float*)d_in[13];
    const float* bout = (const float*)d_in[14];

    __hip_bfloat16* adjP = (__hip_bfloat16*)d_ws;   // 4*96*96*2 = 73,728 B (r0-5 proven)
    float* out0   = (float*)d_out;
    float* out_fn = out0 + (size_t)B_TOTAL * NN * OUTC;

    prep_adj_kernel<<<(2 * KP * KP + 255) / 256, 256, 0, stream>>>(in_adj, out_adj, adjP);

    int grid = (B_TOTAL + NB - 1) / NB;             // 4096
    ggnn_kernel<<<grid, THREADS, 0, stream>>>(
        x, adjP, w3w, b3w, w3u, b3u, w4w, b4w, w5w, b5w, w5u, b5u,
        wout, bout, out0, out_fn);
}